// Round 18
// baseline (3076.546 us; speedup 1.0000x reference)
//
#include <hip/hip_runtime.h>

typedef unsigned short u16;
typedef unsigned long long u64;
typedef __attribute__((ext_vector_type(8))) short bf16x8;
typedef __attribute__((ext_vector_type(4))) float f32x4;

#define DEVI __device__ __forceinline__

#define KSC 0.1803368801111244f  /* 0.125 * log2(e), folded into QU/QV */

DEVI u16 f2b(float f) {
  unsigned u = __float_as_uint(f);
  u += 0x7fffu + ((u >> 16) & 1u);
  return (u16)(u >> 16);
}
DEVI float b2f(u16 v) { return __uint_as_float((unsigned)v << 16); }
DEVI unsigned cvtpk(float lo, float hi) {  // packs 2xbf16 (RNE) in 1 inst
  unsigned r;
  asm("v_cvt_pk_bf16_f32 %0, %1, %2" : "=v"(r) : "v"(lo), "v"(hi));
  return r;
}
DEVI float tanh_f(float x) {
  float xc = fminf(fmaxf(x, -15.f), 15.f);
  float e = __expf(2.f * xc);
  return (e - 1.f) / (e + 1.f);
}
DEVI float gelu_f(float x) {
  float u = 0.7978845608028654f * x * (1.f + 0.044715f * x * x);
  return 0.5f * x * (1.f + tanh_f(u));
}
DEVI float sigm_f(float x) { return 1.f / (1.f + __expf(-x)); }

DEVI void gload16(const void* g, void* l) {
  __builtin_amdgcn_global_load_lds((__attribute__((address_space(1))) void*)g,
                                   (__attribute__((address_space(3))) void*)l, 16, 0, 0);
}

// ---------------------------------------------------------------------------
// Generic batched GEMM, tile 128 x BN.
//  <256,64,4,2>: 4 waves, per-wave 64x32, 2-buffer 2-phase (round-8 proven).
//  <512,64,2,3>: 8 waves, per-wave 32x32, 3-buffer distance-2 prefetch:
//     stage(t+2); compute(t); vmcnt(3) [t+1 landed, t+2 in flight]; barrier.
//     72KB LDS -> 2 blocks/CU (fixes r16's 1-blk/CU occupancy failure while
//     keeping the counted-vmcnt pipeline mechanism).
// ---------------------------------------------------------------------------
template <int NT, int BN, int MF, int NBUF>
__global__ __launch_bounds__(NT) void gemm_bt(
    const u16* __restrict__ A, const u16* __restrict__ Bt,
    const float* __restrict__ bias, const float* __restrict__ bias2,
    float* __restrict__ C32, u16* __restrict__ C16, u16* __restrict__ C16b,
    int M, int N, int K, int ldA, int ldB, int ldC,
    long long sA, long long sBb, long long sBh, long long sC, int nH, int flags)
{
  constexpr int WN = BN / 32;            // waves along n
  constexpr int RA = (128 * 8) / NT;     // A stage rounds
  constexpr int RB = (BN * 8) / NT;      // B stage rounds
  static_assert(NBUF == 2 || (NBUF == 3 && RA + RB == 3), "vmcnt literal");
  static_assert(MF * 16 * ((NT / 64) / WN) == 128, "wave tiling");
  __shared__ __align__(16) u16 Sm[NBUF][(128 + BN) * 64];
  const int z = blockIdx.z;
  const int zb = z / nH, zh = z - zb * nH;
  A  += (long long)z * sA;
  Bt += (long long)zb * sBb + (long long)zh * sBh;
  const long long cOff = (long long)z * sC;
  const int m0 = blockIdx.x * 128, n0 = blockIdx.y * BN;
  const int t = threadIdx.x, lane = t & 63;
  const int w = t >> 6;
  const int wm = (w / WN) * (MF * 16), wn = (w % WN) * 32;

  f32x4 acc[MF][2];
#pragma unroll
  for (int i = 0; i < MF; ++i)
#pragma unroll
    for (int j = 0; j < 2; ++j) { f32x4 zz = {0.f, 0.f, 0.f, 0.f}; acc[i][j] = zz; }

  auto stage = [&](int buf, int k0) {
#pragma unroll
    for (int r = 0; r < RA; ++r) {
      const int c = r * NT + t;
      const int row = c >> 3;
      const int col = (c & 7) << 3;
      int ga = m0 + row; if (ga >= M) ga = M - 1;
      gload16(A + (long long)ga * ldA + (k0 + col),
              &Sm[buf][(size_t)(r * NT + (t & (NT - 64))) * 8]);
    }
#pragma unroll
    for (int r = 0; r < RB; ++r) {
      const int c = r * NT + t;
      const int row = c >> 3;
      const int col = (c & 7) << 3;
      int gb = n0 + row; if (gb >= N) gb = N - 1;
      gload16(Bt + (long long)gb * ldB + (k0 + col),
              &Sm[buf][(size_t)(1024 + r * NT + (t & (NT - 64))) * 8]);
    }
  };

  auto compute = [&](int buf) {
    const u16* As = &Sm[buf][0];
    const u16* Bs = &Sm[buf][128 * 64];
#pragma unroll
    for (int ks = 0; ks < 2; ++ks) {
      const int ko = ks * 32 + ((lane >> 4) << 3);
      bf16x8 af[MF], bfv[2];
#pragma unroll
      for (int i = 0; i < MF; ++i)
        af[i] = *(const bf16x8*)&As[(wm + i * 16 + (lane & 15)) * 64 + ko];
#pragma unroll
      for (int i = 0; i < 2; ++i)
        bfv[i] = *(const bf16x8*)&Bs[(wn + i * 16 + (lane & 15)) * 64 + ko];
#pragma unroll
      for (int mi = 0; mi < MF; ++mi)
#pragma unroll
        for (int ni = 0; ni < 2; ++ni)
          acc[mi][ni] = __builtin_amdgcn_mfma_f32_16x16x32_bf16(af[mi], bfv[ni], acc[mi][ni], 0, 0, 0);
    }
  };

  if constexpr (NBUF == 2) {
    stage(0, 0);
    __syncthreads();
    int cur = 0;
    for (int k0 = 64; k0 < K; k0 += 64) {
      stage(cur ^ 1, k0);
      compute(cur);
      __syncthreads();
      cur ^= 1;
    }
    compute(cur);
  } else {
    const int nk = K >> 6;
    stage(0, 0);
    if (nk > 1) {
      stage(1, 64);
      asm volatile("s_waitcnt vmcnt(3)" ::: "memory");   // tile0 landed; tile1 flying
    } else {
      asm volatile("s_waitcnt vmcnt(0)" ::: "memory");
    }
    __builtin_amdgcn_s_barrier();
    for (int tt = 0; tt < nk; ++tt) {
      if (tt + 2 < nk) stage((tt + 2) % 3, (tt + 2) << 6);   // dist-2 prefetch
      compute(tt % 3);
      if (tt + 1 < nk) {
        if (tt + 2 < nk)
          asm volatile("s_waitcnt vmcnt(3)" ::: "memory");   // t+1 landed; t+2 flying
        else
          asm volatile("s_waitcnt vmcnt(0)" ::: "memory");   // tail drain
        __builtin_amdgcn_s_barrier();
      }
    }
  }

  const int cb = n0 + wn + (lane & 15);
  const int rb = m0 + wm + ((lane >> 4) << 2);
#pragma unroll
  for (int ni = 0; ni < 2; ++ni) {
    const int col = cb + ni * 16;
    if (col >= N) continue;
    float bv = 0.f;
    if (flags & 2) bv = ((flags & 128) && zh) ? bias2[col] : bias[col];
#pragma unroll
    for (int mi = 0; mi < MF; ++mi) {
#pragma unroll
      for (int q = 0; q < 4; ++q) {
        const int row = rb + mi * 16 + q;
        if (row >= M) continue;
        float x = acc[mi][ni][q] + bv;
        if (flags & 1) x = gelu_f(x);
        if (flags & 64) {
          const long long o = ((long long)((row & 7) * 16 + (col >> 6)) * ldC + (row >> 3)) * 64 + (col & 63);
          C16[o] = f2b(x * KSC);
          C16b[o] = f2b((x + bias2[col]) * KSC);
        } else if (flags & 128) {
          if (zh == 0) {
            const long long o = ((long long)((row & 7) * 16 + (col >> 6)) * ldC + (row >> 3)) * 64 + (col & 63);
            C16[o] = f2b(x);
          } else {
            C16b[(long long)row * 1024 + col] = f2b(x);
          }
        } else {
          long long o;
          if (flags & 16)
            o = ((long long)((row & 7) * 16 + (col >> 6)) * ldC + (row >> 3)) * 64 + (col & 63);
          else if (flags & 32)
            o = ((long long)(col >> 6) * 1024 + row) * 64 + (col & 63);
          else
            o = cOff + (long long)row * ldC + col;
          if (flags & 4) C32[o] = x;
          if (flags & 8) C16[o] = f2b(x);
        }
      }
    }
  }
}

// ---------------------------------------------------------------------------
// Fused rel-pos attention (round-14 best: dbuf pipeline + T13 defer-max).
// ---------------------------------------------------------------------------
__global__ __launch_bounds__(256) void fused_attn(
    const u16* __restrict__ Qu,   // [b][h][s][64] (pre-scaled by KSC)
    const u16* __restrict__ Qv,   // [b][h][s][64] (pre-scaled by KSC)
    const u16* __restrict__ Kb,   // [b][h][f][64]
    const u16* __restrict__ Vt,   // [bh][d][1024]
    const u16* __restrict__ Rh,   // [h][c][64]
    u16* __restrict__ Y)           // [s][b*1024 + h*64 + d]
{
  constexpr int F = 1024;
  const int bid = blockIdx.x;                   // 1024 blocks
  const int wk = (bid & 7) * 128 + (bid >> 3);  // XCD-bijective swizzle
  const int i0 = (wk & 7) * 64;
  const int bh = wk >> 3;
  const int h = bh & 15;

  __shared__ __align__(16) u16 Ks[2][64 * 64];
  __shared__ __align__(16) u16 Vs[2][64 * 64];
  __shared__ __align__(16) u16 Rs[2][64 * 64];
  __shared__ __align__(8) u16 PBT[2][64 * 68];
  __shared__ __align__(16) u16 Ps[4][16][72];

  const int t = threadIdx.x;
  const int lane = t & 63;
  const int wq = t >> 6;
  const int l15 = lane & 15, lhi = lane >> 4;

  const u16* QUg = Qu + ((size_t)bh * 512 + i0) * 64;
  const u16* QVg = Qv + ((size_t)bh * 512 + i0) * 64;
  const u16* Kg = Kb + (size_t)bh * F * 64;
  const u16* Vg = Vt + (size_t)bh * 64 * F;
  const u16* Rg = Rh + (size_t)h * F * 64;

  bf16x8 au[2], av[2];
#pragma unroll
  for (int ks = 0; ks < 2; ++ks) {
    const int arow = wq * 16 + l15;
    au[ks] = *(const bf16x8*)(QUg + arow * 64 + ks * 32 + lhi * 8);
    av[ks] = *(const bf16x8*)(QVg + arow * 64 + ks * 32 + lhi * 8);
  }

  auto stageT = [&](const u16* g, u16* dst) {
#pragma unroll
    for (int rnd = 0; rnd < 2; ++rnd) {
      const int idx = rnd * 256 + t;
      const int row = idx >> 3;
      const int gs = (idx & 7) ^ (row & 7);
      gload16(g + row * 64 + gs * 8, dst + (size_t)(rnd * 256 + (t & 192)) * 8);
    }
  };
  auto stageVf = [&](int j0, u16* dst) {
#pragma unroll
    for (int rnd = 0; rnd < 2; ++rnd) {
      const int idx = rnd * 256 + t;
      const int row = idx >> 3;
      const int gs = (idx & 7) ^ (row & 7);
      gload16(Vg + (size_t)row * F + j0 + gs * 8, dst + (size_t)(rnd * 256 + (t & 192)) * 8);
    }
  };

  const int nT = i0 / 64 + 9;

  // ---- prologue ----
  stageT(Kg, Ks[0]);
  stageVf(0, Vs[0]);
  stageT(Rg + (size_t)(512 - i0) * 64, Rs[0]);   // hi band for tile 0
  stageT(Rg + (size_t)(448 - i0) * 64, Rs[1]);   // lo band for tile 0 (temp)
  __syncthreads();
  {
    f32x4 pb0[4];
#pragma unroll
    for (int i = 0; i < 4; ++i) { f32x4 zz = {0.f, 0.f, 0.f, 0.f}; pb0[i] = zz; }
    __builtin_amdgcn_s_setprio(1);
#pragma unroll
    for (int ks = 0; ks < 2; ++ks)
#pragma unroll
      for (int ni = 0; ni < 4; ++ni) {
        const int brow = ni * 16 + l15;
        const bf16x8 br_ = *(const bf16x8*)&Rs[1][brow * 64 + (((ks * 4 + lhi) ^ (brow & 7)) << 3)];
        pb0[ni] = __builtin_amdgcn_mfma_f32_16x16x32_bf16(av[ks], br_, pb0[ni], 0, 0, 0);
      }
    __builtin_amdgcn_s_setprio(0);
#pragma unroll
    for (int ni = 0; ni < 4; ++ni) {
      u64 w = (u64)cvtpk(pb0[ni][0], pb0[ni][1]) | ((u64)cvtpk(pb0[ni][2], pb0[ni][3]) << 32);
      *(u64*)&PBT[0][(size_t)(ni * 16 + l15) * 68 + wq * 16 + lhi * 4] = w;
    }
  }
  __syncthreads();   // all waves done with Rs[1] before iter0 overwrites it

  f32x4 Oacc[4];
#pragma unroll
  for (int i = 0; i < 4; ++i) { f32x4 zz = {0.f, 0.f, 0.f, 0.f}; Oacc[i] = zz; }
  float mrow[4] = {-3.0e38f, -3.0e38f, -3.0e38f, -3.0e38f};
  float lrow[4] = {0.f, 0.f, 0.f, 0.f};

  for (int st = 0; st < nT; ++st) {
    const int b = st & 1;
    const bool lastT = (st == nT - 1);

    if (!lastT) {
      const int j1 = (st + 1) * 64;
      stageT(Kg + (size_t)j1 * 64, Ks[b ^ 1]);
      stageVf(j1, Vs[b ^ 1]);
      if (st + 1 < nT - 1)
        stageT(Rg + (size_t)(j1 - i0 + 512) * 64, Rs[b ^ 1]);
    }

    f32x4 cacc[4], pbh[4];
#pragma unroll
    for (int i = 0; i < 4; ++i) {
      f32x4 zz = {0.f, 0.f, 0.f, 0.f};
      cacc[i] = zz; pbh[i] = zz;
    }
    __builtin_amdgcn_s_setprio(1);
#pragma unroll
    for (int ks = 0; ks < 2; ++ks) {
#pragma unroll
      for (int ni = 0; ni < 4; ++ni) {
        const int brow = ni * 16 + l15;
        const bf16x8 bk_ = *(const bf16x8*)&Ks[b][brow * 64 + (((ks * 4 + lhi) ^ (brow & 7)) << 3)];
        cacc[ni] = __builtin_amdgcn_mfma_f32_16x16x32_bf16(au[ks], bk_, cacc[ni], 0, 0, 0);
      }
      if (!lastT) {
#pragma unroll
        for (int ni = 0; ni < 4; ++ni) {
          const int brow = ni * 16 + l15;
          const bf16x8 br_ = *(const bf16x8*)&Rs[b][brow * 64 + (((ks * 4 + lhi) ^ (brow & 7)) << 3)];
          pbh[ni] = __builtin_amdgcn_mfma_f32_16x16x32_bf16(av[ks], br_, pbh[ni], 0, 0, 0);
        }
      }
    }
    __builtin_amdgcn_s_setprio(0);

    if (!lastT) {
#pragma unroll
      for (int ni = 0; ni < 4; ++ni) {
        u64 w = (u64)cvtpk(pbh[ni][0], pbh[ni][1]) | ((u64)cvtpk(pbh[ni][2], pbh[ni][3]) << 32);
        *(u64*)&PBT[(st + 1) & 1][(size_t)(ni * 16 + l15) * 68 + wq * 16 + lhi * 4] = w;
      }
    }

    // ---- scores: add-only (pre-scaled); mask only on last tile ----
    const u16* pbLo = &PBT[st & 1][0];
    const u16* pbHi = &PBT[(st + 1) & 1][0];
    float sc[4][4];
#pragma unroll
    for (int ni = 0; ni < 4; ++ni) {
      const int dj = ni * 16 + l15;
#pragma unroll
      for (int qq = 0; qq < 4; ++qq) {
        const int di = wq * 16 + lhi * 4 + qq;
        const int cc = dj - di + 63;
        const float pb = b2f((cc < 64) ? pbLo[(size_t)cc * 68 + di]
                                       : pbHi[(size_t)(cc - 64) * 68 + di]);
        float s = cacc[ni][qq] + pb;
        if (lastT && dj > di) s = -1e30f;
        sc[ni][qq] = s;
      }
    }

    // ---- online softmax with T13 defer-max ----
    float r4[4];
    float dmax = -3.0e38f;
#pragma unroll
    for (int qq = 0; qq < 4; ++qq) {
      float r = fmaxf(fmaxf(sc[0][qq], sc[1][qq]), fmaxf(sc[2][qq], sc[3][qq]));
      r = fmaxf(r, __shfl_xor(r, 1));
      r = fmaxf(r, __shfl_xor(r, 2));
      r = fmaxf(r, __shfl_xor(r, 4));
      r = fmaxf(r, __shfl_xor(r, 8));
      r4[qq] = r;
      dmax = fmaxf(dmax, r - mrow[qq]);
    }
    const bool skip = __all(dmax <= 8.f);   // wave-uniform
    if (!skip) {
#pragma unroll
      for (int qq = 0; qq < 4; ++qq) {
        const float nm = fmaxf(mrow[qq], r4[qq]);
        const float esc = exp2f(mrow[qq] - nm);
        mrow[qq] = nm;
        lrow[qq] *= esc;
#pragma unroll
        for (int nd = 0; nd < 4; ++nd) Oacc[nd][qq] *= esc;
      }
    }
    float ps[4][4];
    float rsum[4] = {0.f, 0.f, 0.f, 0.f};
#pragma unroll
    for (int ni = 0; ni < 4; ++ni)
#pragma unroll
      for (int qq = 0; qq < 4; ++qq) {
        float p = exp2f(sc[ni][qq] - mrow[qq]);
        ps[ni][qq] = p;
        rsum[qq] += p;
      }
#pragma unroll
    for (int qq = 0; qq < 4; ++qq) {
      float r = rsum[qq];
      r += __shfl_xor(r, 1);
      r += __shfl_xor(r, 2);
      r += __shfl_xor(r, 4);
      r += __shfl_xor(r, 8);
      lrow[qq] += r;
    }

    // ---- P -> LDS (cvt_pk) -> PV MFMA ----
#pragma unroll
    for (int ni = 0; ni < 4; ++ni) {
      unsigned p01 = cvtpk(ps[ni][0], ps[ni][1]);
      unsigned p23 = cvtpk(ps[ni][2], ps[ni][3]);
      Ps[wq][lhi * 4 + 0][ni * 16 + l15] = (u16)p01;
      Ps[wq][lhi * 4 + 1][ni * 16 + l15] = (u16)(p01 >> 16);
      Ps[wq][lhi * 4 + 2][ni * 16 + l15] = (u16)p23;
      Ps[wq][lhi * 4 + 3][ni * 16 + l15] = (u16)(p23 >> 16);
    }
    __builtin_amdgcn_s_setprio(1);
#pragma unroll
    for (int ks = 0; ks < 2; ++ks) {
      const bf16x8 pa = *(const bf16x8*)&Ps[wq][l15][ks * 32 + lhi * 8];
#pragma unroll
      for (int nd = 0; nd < 4; ++nd) {
        const int vrow = nd * 16 + l15;
        const bf16x8 vb_ = *(const bf16x8*)&Vs[b][vrow * 64 + (((ks * 4 + lhi) ^ (vrow & 7)) << 3)];
        Oacc[nd] = __builtin_amdgcn_mfma_f32_16x16x32_bf16(pa, vb_, Oacc[nd], 0, 0, 0);
      }
    }
    __builtin_amdgcn_s_setprio(0);

    __syncthreads();
  }

  // epilogue
  float inv[4];
#pragma unroll
  for (int qq = 0; qq < 4; ++qq) inv[qq] = 1.f / lrow[qq];
  const int b = bh >> 4;
  const int rbase = i0 + wq * 16 + lhi * 4;
#pragma unroll
  for (int nd = 0; nd < 4; ++nd) {
    const int d = nd * 16 + l15;
    unsigned w01 = cvtpk(Oacc[nd][0] * inv[0], Oacc[nd][1] * inv[1]);
    unsigned w23 = cvtpk(Oacc[nd][2] * inv[2], Oacc[nd][3] * inv[3]);
    u16* yb = Y + (size_t)rbase * 8192 + b * 1024 + h * 64 + d;
    yb[0] = (u16)w01; yb[8192] = (u16)(w01 >> 16);
    yb[16384] = (u16)w23; yb[24576] = (u16)(w23 >> 16);
  }
}

// ---------------------------------------------------------------------------
__global__ __launch_bounds__(256) void biasprep(const float* __restrict__ bq,
                                                const float* __restrict__ u,
                                                const float* __restrict__ vb,
                                                float* __restrict__ bqu,
                                                float* __restrict__ dvb)
{
  const int i = blockIdx.x * 256 + threadIdx.x;
  bqu[i] = bq[i] + u[i];
  dvb[i] = vb[i] - u[i];
}

// ---------------------------------------------------------------------------
#define MAXW 20
struct WPack {
  const float* src[MAXW];
  u16* dst[MAXW];
  int K[MAXW], N[MAXW];
  int tilePrefix[MAXW + 1];
  int nm;
};

__global__ __launch_bounds__(256) void wtrans_kernel(WPack p) {
  int bid = blockIdx.x;
  int m = 0;
  while (m < p.nm && bid >= p.tilePrefix[m + 1]) ++m;
  if (m >= p.nm) return;
  const int lt = bid - p.tilePrefix[m];
  const int K = p.K[m], N = p.N[m];
  const int tN = N >> 5;
  const int kt = lt / tN, nt = lt - kt * tN;
  const int k0 = kt << 5, n0 = nt << 5;
  const float* src = p.src[m];
  u16* dst = p.dst[m];
  __shared__ float tile[32][33];
  const int t = threadIdx.x;
  const int r = t >> 3, c4 = (t & 7) << 2;
  float4 v = *(const float4*)&src[(size_t)(k0 + r) * N + n0 + c4];
  tile[r][c4 + 0] = v.x; tile[r][c4 + 1] = v.y; tile[r][c4 + 2] = v.z; tile[r][c4 + 3] = v.w;
  __syncthreads();
  u16 o0 = f2b(tile[c4 + 0][r]);
  u16 o1 = f2b(tile[c4 + 1][r]);
  u16 o2 = f2b(tile[c4 + 2][r]);
  u16 o3 = f2b(tile[c4 + 3][r]);
  u64 w = (u64)o0 | ((u64)o1 << 16) | ((u64)o2 << 32) | ((u64)o3 << 48);
  *(u64*)&dst[(size_t)(n0 + r) * K + k0 + c4] = w;
}

// ---------------------------------------------------------------------------
__global__ __launch_bounds__(256) void ln_kernel(
    const float* __restrict__ Xmem, const float* __restrict__ Xout, int rowsMem,
    const float* __restrict__ sc, const float* __restrict__ bi, u16* __restrict__ dst)
{
  const int row = blockIdx.x;
  const float* src = (row < rowsMem) ? (Xmem + (long long)row * 1024)
                                     : (Xout + (long long)(row - rowsMem) * 1024);
  const int t = threadIdx.x;
  float4 v = *(const float4*)&src[t * 4];
  float s1 = v.x + v.y + v.z + v.w;
  float s2 = v.x * v.x + v.y * v.y + v.z * v.z + v.w * v.w;
#pragma unroll
  for (int o = 32; o > 0; o >>= 1) { s1 += __shfl_down(s1, o); s2 += __shfl_down(s2, o); }
  __shared__ float red[8];
  const int wv = t >> 6;
  if ((t & 63) == 0) { red[wv * 2] = s1; red[wv * 2 + 1] = s2; }
  __syncthreads();
  s1 = red[0] + red[2] + red[4] + red[6];
  s2 = red[1] + red[3] + red[5] + red[7];
  const float mu = s1 * (1.f / 1024.f);
  const float var = s2 * (1.f / 1024.f) - mu * mu;
  const float rs = rsqrtf(var + 1e-5f);
  float vals[4] = {v.x, v.y, v.z, v.w};
  u16 o4[4];
#pragma unroll
  for (int j = 0; j < 4; ++j) {
    const int c = t * 4 + j;
    o4[j] = f2b((vals[j] - mu) * rs * sc[c] + bi[c]);
  }
  *(u64*)&dst[(long long)row * 1024 + t * 4] =
      (u64)o4[0] | ((u64)o4[1] << 16) | ((u64)o4[2] << 32) | ((u64)o4[3] << 48);
}

// ---------------------------------------------------------------------------
__global__ __launch_bounds__(256) void prep_vt16(const u16* __restrict__ Vf, u16* __restrict__ VT)
{
  const int f0 = blockIdx.x * 64;
  const int bh = blockIdx.y;
  const int b = bh >> 4, h = bh & 15;
  __shared__ u16 tl[64 * 65];
  const int t = threadIdx.x;
  {
    const int fr = t >> 2, c0 = (t & 3) * 16;
    const u16* src = Vf + ((size_t)(f0 + fr) * 8 + b) * 1024 + h * 64 + c0;
    bf16x8 v0 = *(const bf16x8*)src;
    bf16x8 v1 = *(const bf16x8*)(src + 8);
#pragma unroll
    for (int j = 0; j < 8; ++j) tl[fr * 65 + c0 + j] = (u16)v0[j];
#pragma unroll
    for (int j = 0; j < 8; ++j) tl[fr * 65 + c0 + 8 + j] = (u16)v1[j];
  }
  __syncthreads();
  {
    const int dr = t >> 2, c0 = (t & 3) * 16;
    u16* dst = VT + ((long long)bh * 64 + dr) * 1024 + f0 + c0;
#pragma unroll
    for (int j = 0; j < 16; ++j) dst[j] = tl[(c0 + j) * 65 + dr];
  }
}

__global__ __launch_bounds__(256) void pe_kernel(u16* __restrict__ PEB)
{
  const long long idx = (long long)blockIdx.x * 256 + threadIdx.x;
  const int p = (int)(idx >> 10);
  const int d = idx & 1023;
  const int q = d & 511;
  const float inv = powf(10000.f, -(float)(2 * q) * (1.f / 1024.f));
  const float ang = (float)(1023 - p) * inv;
  PEB[idx] = f2b((d < 512) ? sinf(ang) : cosf(ang));
}

__global__ __launch_bounds__(256) void embed_conv(const float* __restrict__ h, u16* __restrict__ A)
{
  const long long idx = (long long)blockIdx.x * 256 + threadIdx.x;
  const int c = idx & 127;
  const int r = (int)(idx >> 7);
  const int s = r >> 3, b = r & 7;
  A[idx] = f2b(h[(((long long)b * 512 + s) << 7) + c]);
}

// ---------------------------------------------------------------------------
// GRU elementwise, bf16 temps, 8 el/thread.
// ---------------------------------------------------------------------------
__global__ __launch_bounds__(256) void gru_elemA(const u16* __restrict__ T1, u16* __restrict__ T2,
                                                 const float* __restrict__ X, u16* __restrict__ RXBF)
{
  const long long i8 = ((long long)blockIdx.x * 256 + threadIdx.x) * 8;
  const int row = (int)(i8 >> 10);
  const int c = i8 & 1023;
  const u16* t1 = T1 + (long long)row * 3072 + c;
  u16* t2 = T2 + (long long)row * 2048 + c;
  bf16x8 ry = *(const bf16x8*)t1;
  bf16x8 zy = *(const bf16x8*)(t1 + 1024);
  bf16x8 rx = *(const bf16x8*)t2;
  bf16x8 zx = *(const bf16x8*)(t2 + 1024);
  float4 x0 = *(const float4*)(X + i8);
  float4 x1 = *(const float4*)(X + i8 + 4);
  float xs[8] = {x0.x, x0.y, x0.z, x0.w, x1.x, x1.y, x1.z, x1.w};
  u16 ro[8], zo[8];
#pragma unroll
  for (int j = 0; j < 8; ++j) {
    float r = sigm_f(b2f((u16)ry[j]) + b2f((u16)rx[j]));
    float z = sigm_f(b2f((u16)zy[j]) + b2f((u16)zx[j]) - 2.f);
    ro[j] = f2b(r * xs[j]);
    zo[j] = f2b(z);
  }
  *(u64*)&RXBF[i8] = (u64)ro[0] | ((u64)ro[1] << 16) | ((u64)ro[2] << 32) | ((u64)ro[3] << 48);
  *(u64*)&RXBF[i8 + 4] = (u64)ro[4] | ((u64)ro[5] << 16) | ((u64)ro[6] << 32) | ((u64)ro[7] << 48);
  *(u64*)&t2[0] = (u64)zo[0] | ((u64)zo[1] << 16) | ((u64)zo[2] << 32) | ((u64)zo[3] << 48);
  *(u64*)&t2[4] = (u64)zo[4] | ((u64)zo[5] << 16) | ((u64)zo[6] << 32) | ((u64)zo[7] << 48);
}

// tOut: 0 -> O[row][c] flat; 1 -> O[(b*512+s)][c] transposed (final output)
__global__ __launch_bounds__(256) void gru_elemB(const u16* __restrict__ T1, const u16* __restrict__ T2,
                                                 const u16* __restrict__ TG, const float* __restrict__ X,
                                                 float* __restrict__ O, u16* __restrict__ XBF, int tOut)
{
  const long long i8 = ((long long)blockIdx.x * 256 + threadIdx.x) * 8;
  const int row = (int)(i8 >> 10);
  const int c = i8 & 1023;
  bf16x8 gy = *(const bf16x8*)(T1 + (long long)row * 3072 + 2048 + c);
  bf16x8 tt = *(const bf16x8*)(TG + i8);
  bf16x8 zz = *(const bf16x8*)(T2 + (long long)row * 2048 + c);
  float4 x0 = *(const float4*)(X + i8);
  float4 x1 = *(const float4*)(X + i8 + 4);
  float xs[8] = {x0.x, x0.y, x0.z, x0.w, x1.x, x1.y, x1.z, x1.w};
  float os[8];
  u16 ob[8];
#pragma unroll
  for (int j = 0; j < 8; ++j) {
    float z = b2f((u16)zz[j]);
    float o = (1.f - z) * xs[j] + z * tanh_f(b2f((u16)gy[j]) + b2f((u16)tt[j]));
    os[j] = o;
    ob[j] = f2b(o);
  }
  float4 o0 = {os[0], os[1], os[2], os[3]};
  float4 o1 = {os[4], os[5], os[6], os[7]};
  long long oo = i8;
  if (tOut) {
    const int s = row >> 3, b = row & 7;
    oo = (((long long)b * 512 + s) << 10) + c;
  }
  *(float4*)(O + oo) = o0;
  *(float4*)(O + oo + 4) = o1;
  *(u64*)&XBF[i8] = (u64)ob[0] | ((u64)ob[1] << 16) | ((u64)ob[2] << 32) | ((u64)ob[3] << 48);
  *(u64*)&XBF[i8 + 4] = (u64)ob[4] | ((u64)ob[5] << 16) | ((u64)ob[6] << 32) | ((u64)ob[7] << 48);
}

// ---------------------------------------------------------------------------
extern "C" void kernel_launch(void* const* d_in, const int* in_sizes, int n_in,
                              void* d_out, int out_size, void* d_ws, size_t ws_size,
                              hipStream_t stream)
{
  (void)in_sizes; (void)n_in; (void)out_size; (void)ws_size;
  const float* h_in   = (const float*)d_in[0];
  const float* memory = (const float*)d_in[1];
  const float* We     = (const float*)d_in[2];
  const float* be     = (const float*)d_in[3];
  const float* ln1s   = (const float*)d_in[4];
  const float* ln1b   = (const float*)d_in[5];
  const float* ln2s   = (const float*)d_in[6];
  const float* ln2b   = (const float*)d_in[7];
  const float* Wq     = (const float*)d_in[8];
  const float* bq     = (const float*)d_in[9];
  const float* Wk     = (const float*)d_in[10];
  const float* bk     = (const float*)d_in[11];
  const float* Wv     = (const float*)d_in[12];
  const float* bv     = (const float*)d_in[13];
  const float* Wr     = (const float*)d_in[14];
  const float* br     = (const float*)d_in[15];
  const float* Wo     = (const float*)d_in[16];
  const float* bo     = (const float*)d_in[17];
  const float* uu     = (const float*)d_in[18];
  const float* vbp    = (const float*)d_in[19];
  const float* gWr    = (const float*)d_in[20];
  const float* gUr    = (const float*)d_in[21];
  const float* gWz    = (const float*)d_in[22];
  const float* gUz    = (const float*)d_in[23];
  const float* gWg    = (const float*)d_in[24];
  const float* gUg    = (const float*)d_in[25];
  const float* fW1    = (const float*)d_in[26];
  const float* fb1    = (const float*)d_in[27];
  const float* fW2    = (const float*)d_in[28];
  const float* fb2    = (const float*)d_in[29];

  constexpr int S = 512, MM = 512, B = 8, D = 1024, H = 16, IN = 128, F = 1024;
  constexpr int SB = 4096, FB = 8192;
  constexpr long long DD = (long long)D * D;

  char* ws = (char*)d_ws;
  size_t off = 0;
  auto alloc = [&](size_t bytes) -> size_t {
    size_t o = off; off = (off + bytes + 255) & ~(size_t)255; return o;
  };
  const size_t oWT   = alloc((size_t)25 * DD * 2);
  const size_t oWET  = alloc((size_t)D * IN * 2);
  const size_t oPEB  = alloc((size_t)F * D * 2);
  const size_t oOUT  = alloc((size_t)SB * D * 4);
  const size_t oOUT1 = alloc((size_t)SB * D * 4);
  const size_t oXBF  = alloc((size_t)SB * D * 2);
  const size_t oYBF  = alloc((size_t)SB * D * 2);
  const size_t oYBFA = alloc((size_t)SB * D * 2);
  const size_t oABUF = alloc((size_t)SB * D * 2);
  const size_t oKN   = alloc((size_t)FB * D * 2);
  const size_t oQU   = alloc((size_t)B * H * S * 64 * 2);
  const size_t oQV   = alloc((size_t)B * H * S * 64 * 2);
  const size_t oKBH  = alloc((size_t)B * H * F * 64 * 2);
  const size_t oVT   = alloc((size_t)B * H * F * 64 * 2);
  const size_t oRH   = alloc((size_t)H * F * 64 * 2);
  const size_t oBQU  = alloc((size_t)D * 4);
  const size_t oDVB  = alloc((size_t)D * 4);
  const size_t oUNI  = off;

  u16* WTp   = (u16*)(ws + oWT);
  u16* WETp  = (u16*)(ws + oWET);
  u16* PEBp  = (u16*)(ws + oPEB);
  float* OUTp  = (float*)(ws + oOUT);
  float* OUT1p = (float*)(ws + oOUT1);
  u16* XBFp  = (u16*)(ws + oXBF);
  u16* YBFp  = (u16*)(ws + oYBF);
  u16* YBFAp = (u16*)(ws + oYBFA);
  u16* ABUFp = (u16*)(ws + oABUF);
  u16* KNp   = (u16*)(ws + oKN);
  u16* QUp   = (u16*)(ws + oQU);
  u16* QVp   = (u16*)(ws + oQV);
  u16* KBHp  = (u16*)(ws + oKBH);
  u16* VTp   = (u16*)(ws + oVT);
  u16* RHp   = (u16*)(ws + oRH);
  float* bquP = (float*)(ws + oBQU);
  float* dvbP = (float*)(ws + oDVB);
  u16* VF16p  = (u16*)(ws + oUNI);
  u16* T1p    = (u16*)(ws + oUNI);                                   // SB x 3072 bf16
  u16* T2p    = (u16*)(ws + oUNI + (size_t)SB * 3 * D * 2 + 256);    // SB x 2048 bf16
  u16* TGp    = (u16*)(ws + oUNI + (size_t)SB * 5 * D * 2 + 512);    // SB x 1024 bf16
  u16* FFNBp  = (u16*)(ws + oUNI);

  auto gemm = [&](const u16* A, const u16* Bt, const float* bias, const float* bias2,
                  float* C32, u16* C16, u16* C16b,
                  int M, int N, int K, int ldA, int ldB, int ldC,
                  long long sA, long long sBb, long long sBh, long long sC, int nH, int Z,
                  int flags) {
    if (M >= 2048 && N >= 2048 && (N % 64) == 0) {
      dim3 grid((M + 127) / 128, N / 64, Z);
      gemm_bt<512, 64, 2, 3><<<grid, 512, 0, stream>>>(A, Bt, bias, bias2, C32, C16, C16b,
                                                       M, N, K, ldA, ldB, ldC,
                                                       sA, sBb, sBh, sC, nH, flags);
    } else {
      dim3 grid((M + 127) / 128, (N + 63) / 64, Z);
      gemm_bt<256, 64, 4, 2><<<grid, 256, 0, stream>>>(A, Bt, bias, bias2, C32, C16, C16b,
                                                       M, N, K, ldA, ldB, ldC,
                                                       sA, sBb, sBh, sC, nH, flags);
    }
  };

  pe_kernel<<<(F * D) / 256, 256, 0, stream>>>(PEBp);
  {
    WPack p{};
    p.nm = 1; p.src[0] = We; p.dst[0] = WETp; p.K[0] = IN; p.N[0] = D;
    p.tilePrefix[0] = 0; p.tilePrefix[1] = (IN / 32) * (D / 32);
    wtrans_kernel<<<p.tilePrefix[1], 256, 0, stream>>>(p);
  }
  embed_conv<<<(SB * IN) / 256, 256, 0, stream>>>(h_in, ABUFp);
  gemm(ABUFp, WETp, be, nullptr, OUTp, XBFp, nullptr, SB, D, IN, IN, IN, D,
       0, 0, 0, 0, 1, 1, 1 | 2 | 4 | 8);

  for (int li = 0; li < 4; ++li) {
    WPack p{};
    int nt = 0, id = 0;
    auto addw = [&](const float* s, u16* d, int K, int N) {
      p.src[id] = s; p.dst[id] = d; p.K[id] = K; p.N[id] = N;
      p.tilePrefix[id] = nt; nt += (K / 32) * (N / 32); ++id;
    };
    addw(Wq + li * DD, WTp + 0 * DD, D, D);
    addw(Wk + li * DD, WTp + 1 * DD, D, D);
    addw(Wv + li * DD, WTp + 2 * DD, D, D);
    addw(Wr + li * DD, WTp + 3 * DD, D, D);
    addw(Wo + li * DD, WTp + 4 * DD, D, D);
    addw(gWr + (li * 2 + 0) * DD, WTp + 5 * DD, D, D);
    addw(gWz + (li * 2 + 0) * DD, WTp + 6 * DD, D, D);
    addw(gWg + (li * 2 + 0) * DD, WTp + 7 * DD, D, D);
    addw(gUr + (li * 2 + 0) * DD, WTp + 8 * DD, D, D);
    addw(gUz + (li * 2 + 0) * DD, WTp + 9 * DD, D, D);
    addw(gUg + (li * 2 + 0) * DD, WTp + 10 * DD, D, D);
    addw(gWr + (li * 2 + 1) * DD, WTp + 11 * DD, D, D);
    addw(gWz + (li * 2 + 1) * DD, WTp + 12 * DD, D, D);
    addw(gWg + (li * 2 + 1) * DD, WTp + 13 * DD, D, D);
    addw(gUr + (li * 2 + 1) * DD, WTp + 14 * DD, D, D);
    addw(gUz + (li * 2 + 1) * DD, WTp + 15 * DD, D, D);
    addw(gUg + (li * 2 + 1) * DD, WTp + 16 * DD, D, D);
    addw(fW1 + li * (long long)D * 4096, WTp + 17 * DD, D, 4096);
    addw(fW2 + li * (long long)4096 * D, WTp + 21 * DD, 4096, D);
    p.tilePrefix[id] = nt; p.nm = id;
    wtrans_kernel<<<nt, 256, 0, stream>>>(p);

    ln_kernel<<<FB, 256, 0, stream>>>(memory + (long long)li * MM * B * D, OUTp, MM * B,
                                      ln1s + li * D, ln1b + li * D, KNp);
    const u16* QN = KNp + (size_t)MM * B * D;

    // ---- projections: dual-Q (KSC-scaled) + merged K/V ----
    biasprep<<<4, 256, 0, stream>>>(bq + li * D, uu + li * D, vbp + li * D, bquP, dvbP);
    gemm(QN, WTp + 0 * DD, bquP, dvbP, nullptr, QUp, QVp, SB, D, D, D, D, /*seq*/ S,
         0, 0, 0, 0, 1, 1, 2 | 64);
    gemm(KNp, WTp + 1 * DD, bk + li * D, bv + li * D, nullptr, KBHp, VF16p,
         FB, D, D, D, D, /*seq*/ F, 0, 0, DD, 0, 2, 2, 2 | 128);
    prep_vt16<<<dim3(F / 64, B * H), 256, 0, stream>>>(VF16p, VTp);
    gemm(PEBp, WTp + 3 * DD, br + li * D, nullptr, nullptr, RHp, nullptr,
         F, D, D, D, D, D, 0, 0, 0, 0, 1, 1, 2 | 8 | 32);

    // ---- fused attention ----
    fused_attn<<<dim3((S / 64) * B * H), 256, 0, stream>>>(QUp, QVp, KBHp, VTp, RHp, YBFAp);

    // ---- output projection ----
    gemm(YBFAp, WTp + 4 * DD, bo + li * D, nullptr, nullptr, YBFp, nullptr,
         SB, D, D, D, D, D, 0, 0, 0, 0, 1, 1, 1 | 2 | 8);

    // ---- GRU1 (bf16 temps) ----
    gemm(YBFp, WTp + 5 * DD, nullptr, nullptr, nullptr, T1p, nullptr,
         SB, 3 * D, D, D, D, 3 * D, 0, 0, 0, 0, 1, 1, 8);
    gemm(XBFp, WTp + 8 * DD, nullptr, nullptr, nullptr, T2p, nullptr,
         SB, 2 * D, D, D, D, 2 * D, 0, 0, 0, 0, 1, 1, 8);
    gru_elemA<<<(SB * D / 8) / 256, 256, 0, stream>>>(T1p, T2p, OUTp, ABUFp);
    gemm(ABUFp, WTp + 10 * DD, nullptr, nullptr, nullptr, TGp, nullptr,
         SB, D, D, D, D, D, 0, 0, 0, 0, 1, 1, 8);
    gru_elemB<<<(SB * D / 8) / 256, 256, 0, stream>>>(T1p, T2p, TGp, OUTp, OUT1p, XBFp, 0);

    // ---- FFN ----
    ln_kernel<<<SB, 256, 0, stream>>>(OUT1p, OUT1p, SB, ln2s + li * D, ln2b + li * D, ABUFp);
    gemm(ABUFp, WTp + 17 * DD, fb1 + li * 4096, nullptr, nullptr, FFNBp, nullptr,
         SB, 4096, D, D, D, 4096, 0, 0, 0, 0, 1, 1, 1 | 2 | 8);
    gemm(FFNBp, WTp + 21 * DD, fb2 + li * D, nullptr, nullptr, YBFp, nullptr,
         SB, D, 4096, 4096, 4096, D, 0, 0, 0, 0, 1, 1, 1 | 2 | 8);

    // ---- GRU2 (bf16 temps; last layer writes transposed O to d_out) ----
    gemm(YBFp, WTp + 11 * DD, nullptr, nullptr, nullptr, T1p, nullptr,
         SB, 3 * D, D, D, D, 3 * D, 0, 0, 0, 0, 1, 1, 8);
    gemm(XBFp, WTp + 14 * DD, nullptr, nullptr, nullptr, T2p, nullptr,
         SB, 2 * D, D, D, D, 2 * D, 0, 0, 0, 0, 1, 1, 8);
    gru_elemA<<<(SB * D / 8) / 256, 256, 0, stream>>>(T1p, T2p, OUT1p, ABUFp);
    gemm(ABUFp, WTp + 16 * DD, nullptr, nullptr, nullptr, TGp, nullptr,
         SB, D, D, D, D, D, 0, 0, 0, 0, 1, 1, 8);
    gru_elemB<<<(SB * D / 8) / 256, 256, 0, stream>>>(
        T1p, T2p, TGp, OUT1p, (li == 3) ? (float*)d_out : OUTp, XBFp, (li == 3) ? 1 : 0);
  }
}

// Round 19
// 2868.433 us; speedup vs baseline: 1.0726x; 1.0726x over previous
//
#include <hip/hip_runtime.h>

typedef unsigned short u16;
typedef unsigned long long u64;
typedef __attribute__((ext_vector_type(8))) short bf16x8;
typedef __attribute__((ext_vector_type(4))) float f32x4;

#define DEVI __device__ __forceinline__

#define KSC 0.1803368801111244f  /* 0.125 * log2(e), folded into QU/QV */

DEVI u16 f2b(float f) {
  unsigned u = __float_as_uint(f);
  u += 0x7fffu + ((u >> 16) & 1u);
  return (u16)(u >> 16);
}
DEVI float b2f(u16 v) { return __uint_as_float((unsigned)v << 16); }
DEVI unsigned cvtpk(float lo, float hi) {  // packs 2xbf16 (RNE) in 1 inst
  unsigned r;
  asm("v_cvt_pk_bf16_f32 %0, %1, %2" : "=v"(r) : "v"(lo), "v"(hi));
  return r;
}
DEVI float tanh_f(float x) {
  float xc = fminf(fmaxf(x, -15.f), 15.f);
  float e = __expf(2.f * xc);
  return (e - 1.f) / (e + 1.f);
}
DEVI float gelu_f(float x) {
  float u = 0.7978845608028654f * x * (1.f + 0.044715f * x * x);
  return 0.5f * x * (1.f + tanh_f(u));
}
DEVI float sigm_f(float x) { return 1.f / (1.f + __expf(-x)); }

DEVI void gload16(const void* g, void* l) {
  __builtin_amdgcn_global_load_lds((__attribute__((address_space(1))) void*)g,
                                   (__attribute__((address_space(3))) void*)l, 16, 0, 0);
}

// ---------------------------------------------------------------------------
// Generic batched GEMM (round-8 proven 2-phase loop — FINAL).
// Structure plateau documented: counted-vmcnt (r9), 3-buf 128x128 (r16),
// 3-buf 128x64 (r18) all regressed; 2-phase + 2-3 blocks/CU is the verified
// optimum for this kernel shape family.
// Routing: N<=1024 -> <256,64> ; N>=2048 -> <512,128>.
// ---------------------------------------------------------------------------
template <int NT, int BN>
__global__ __launch_bounds__(NT) void gemm_bt(
    const u16* __restrict__ A, const u16* __restrict__ Bt,
    const float* __restrict__ bias, const float* __restrict__ bias2,
    float* __restrict__ C32, u16* __restrict__ C16, u16* __restrict__ C16b,
    int M, int N, int K, int ldA, int ldB, int ldC,
    long long sA, long long sBb, long long sBh, long long sC, int nH, int flags)
{
  constexpr int WN = BN / 32;            // waves along n
  constexpr int RA = (128 * 8) / NT;     // A stage rounds
  constexpr int RB = (BN * 8) / NT;      // B stage rounds
  __shared__ __align__(16) u16 Sm[2][(128 + BN) * 64];
  const int z = blockIdx.z;
  const int zb = z / nH, zh = z - zb * nH;
  A  += (long long)z * sA;
  Bt += (long long)zb * sBb + (long long)zh * sBh;
  const long long cOff = (long long)z * sC;
  const int m0 = blockIdx.x * 128, n0 = blockIdx.y * BN;
  const int t = threadIdx.x, lane = t & 63;
  const int w = t >> 6;
  const int wm = (w / WN) * 64, wn = (w % WN) * 32;

  f32x4 acc[4][2];
#pragma unroll
  for (int i = 0; i < 4; ++i)
#pragma unroll
    for (int j = 0; j < 2; ++j) { f32x4 zz = {0.f, 0.f, 0.f, 0.f}; acc[i][j] = zz; }

  auto stage = [&](int buf, int k0) {
#pragma unroll
    for (int r = 0; r < RA; ++r) {
      const int c = r * NT + t;
      const int row = c >> 3;
      const int col = (c & 7) << 3;
      int ga = m0 + row; if (ga >= M) ga = M - 1;
      gload16(A + (long long)ga * ldA + (k0 + col),
              &Sm[buf][(size_t)(r * NT + (t & (NT - 64))) * 8]);
    }
#pragma unroll
    for (int r = 0; r < RB; ++r) {
      const int c = r * NT + t;
      const int row = c >> 3;
      const int col = (c & 7) << 3;
      int gb = n0 + row; if (gb >= N) gb = N - 1;
      gload16(Bt + (long long)gb * ldB + (k0 + col),
              &Sm[buf][(size_t)(1024 + r * NT + (t & (NT - 64))) * 8]);
    }
  };

  auto compute = [&](int buf) {
    const u16* As = &Sm[buf][0];
    const u16* Bs = &Sm[buf][128 * 64];
#pragma unroll
    for (int ks = 0; ks < 2; ++ks) {
      const int ko = ks * 32 + ((lane >> 4) << 3);
      bf16x8 af[4], bfv[2];
#pragma unroll
      for (int i = 0; i < 4; ++i)
        af[i] = *(const bf16x8*)&As[(wm + i * 16 + (lane & 15)) * 64 + ko];
#pragma unroll
      for (int i = 0; i < 2; ++i)
        bfv[i] = *(const bf16x8*)&Bs[(wn + i * 16 + (lane & 15)) * 64 + ko];
#pragma unroll
      for (int mi = 0; mi < 4; ++mi)
#pragma unroll
        for (int ni = 0; ni < 2; ++ni)
          acc[mi][ni] = __builtin_amdgcn_mfma_f32_16x16x32_bf16(af[mi], bfv[ni], acc[mi][ni], 0, 0, 0);
    }
  };

  stage(0, 0);
  __syncthreads();
  int cur = 0;
  for (int k0 = 64; k0 < K; k0 += 64) {
    stage(cur ^ 1, k0);
    compute(cur);
    __syncthreads();
    cur ^= 1;
  }
  compute(cur);

  const int cb = n0 + wn + (lane & 15);
  const int rb = m0 + wm + ((lane >> 4) << 2);
#pragma unroll
  for (int ni = 0; ni < 2; ++ni) {
    const int col = cb + ni * 16;
    if (col >= N) continue;
    float bv = 0.f;
    if (flags & 2) bv = ((flags & 128) && zh) ? bias2[col] : bias[col];
#pragma unroll
    for (int mi = 0; mi < 4; ++mi) {
#pragma unroll
      for (int q = 0; q < 4; ++q) {
        const int row = rb + mi * 16 + q;
        if (row >= M) continue;
        float x = acc[mi][ni][q] + bv;
        if (flags & 1) x = gelu_f(x);
        if (flags & 64) {
          const long long o = ((long long)((row & 7) * 16 + (col >> 6)) * ldC + (row >> 3)) * 64 + (col & 63);
          C16[o] = f2b(x * KSC);
          C16b[o] = f2b((x + bias2[col]) * KSC);
        } else if (flags & 128) {
          if (zh == 0) {
            const long long o = ((long long)((row & 7) * 16 + (col >> 6)) * ldC + (row >> 3)) * 64 + (col & 63);
            C16[o] = f2b(x);
          } else {
            C16b[(long long)row * 1024 + col] = f2b(x);
          }
        } else {
          long long o;
          if (flags & 16)
            o = ((long long)((row & 7) * 16 + (col >> 6)) * ldC + (row >> 3)) * 64 + (col & 63);
          else if (flags & 32)
            o = ((long long)(col >> 6) * 1024 + row) * 64 + (col & 63);
          else
            o = cOff + (long long)row * ldC + col;
          if (flags & 4) C32[o] = x;
          if (flags & 8) C16[o] = f2b(x);
        }
      }
    }
  }
}

// ---------------------------------------------------------------------------
// Fused rel-pos attention (round-14 best: dbuf pipeline + T13 defer-max).
// ---------------------------------------------------------------------------
__global__ __launch_bounds__(256) void fused_attn(
    const u16* __restrict__ Qu,   // [b][h][s][64] (pre-scaled by KSC)
    const u16* __restrict__ Qv,   // [b][h][s][64] (pre-scaled by KSC)
    const u16* __restrict__ Kb,   // [b][h][f][64]
    const u16* __restrict__ Vt,   // [bh][d][1024]
    const u16* __restrict__ Rh,   // [h][c][64]
    u16* __restrict__ Y)           // [s][b*1024 + h*64 + d]
{
  constexpr int F = 1024;
  const int bid = blockIdx.x;                   // 1024 blocks
  const int wk = (bid & 7) * 128 + (bid >> 3);  // XCD-bijective swizzle
  const int i0 = (wk & 7) * 64;
  const int bh = wk >> 3;
  const int h = bh & 15;

  __shared__ __align__(16) u16 Ks[2][64 * 64];
  __shared__ __align__(16) u16 Vs[2][64 * 64];
  __shared__ __align__(16) u16 Rs[2][64 * 64];
  __shared__ __align__(8) u16 PBT[2][64 * 68];
  __shared__ __align__(16) u16 Ps[4][16][72];

  const int t = threadIdx.x;
  const int lane = t & 63;
  const int wq = t >> 6;
  const int l15 = lane & 15, lhi = lane >> 4;

  const u16* QUg = Qu + ((size_t)bh * 512 + i0) * 64;
  const u16* QVg = Qv + ((size_t)bh * 512 + i0) * 64;
  const u16* Kg = Kb + (size_t)bh * F * 64;
  const u16* Vg = Vt + (size_t)bh * 64 * F;
  const u16* Rg = Rh + (size_t)h * F * 64;

  bf16x8 au[2], av[2];
#pragma unroll
  for (int ks = 0; ks < 2; ++ks) {
    const int arow = wq * 16 + l15;
    au[ks] = *(const bf16x8*)(QUg + arow * 64 + ks * 32 + lhi * 8);
    av[ks] = *(const bf16x8*)(QVg + arow * 64 + ks * 32 + lhi * 8);
  }

  auto stageT = [&](const u16* g, u16* dst) {
#pragma unroll
    for (int rnd = 0; rnd < 2; ++rnd) {
      const int idx = rnd * 256 + t;
      const int row = idx >> 3;
      const int gs = (idx & 7) ^ (row & 7);
      gload16(g + row * 64 + gs * 8, dst + (size_t)(rnd * 256 + (t & 192)) * 8);
    }
  };
  auto stageVf = [&](int j0, u16* dst) {
#pragma unroll
    for (int rnd = 0; rnd < 2; ++rnd) {
      const int idx = rnd * 256 + t;
      const int row = idx >> 3;
      const int gs = (idx & 7) ^ (row & 7);
      gload16(Vg + (size_t)row * F + j0 + gs * 8, dst + (size_t)(rnd * 256 + (t & 192)) * 8);
    }
  };

  const int nT = i0 / 64 + 9;

  // ---- prologue ----
  stageT(Kg, Ks[0]);
  stageVf(0, Vs[0]);
  stageT(Rg + (size_t)(512 - i0) * 64, Rs[0]);   // hi band for tile 0
  stageT(Rg + (size_t)(448 - i0) * 64, Rs[1]);   // lo band for tile 0 (temp)
  __syncthreads();
  {
    f32x4 pb0[4];
#pragma unroll
    for (int i = 0; i < 4; ++i) { f32x4 zz = {0.f, 0.f, 0.f, 0.f}; pb0[i] = zz; }
    __builtin_amdgcn_s_setprio(1);
#pragma unroll
    for (int ks = 0; ks < 2; ++ks)
#pragma unroll
      for (int ni = 0; ni < 4; ++ni) {
        const int brow = ni * 16 + l15;
        const bf16x8 br_ = *(const bf16x8*)&Rs[1][brow * 64 + (((ks * 4 + lhi) ^ (brow & 7)) << 3)];
        pb0[ni] = __builtin_amdgcn_mfma_f32_16x16x32_bf16(av[ks], br_, pb0[ni], 0, 0, 0);
      }
    __builtin_amdgcn_s_setprio(0);
#pragma unroll
    for (int ni = 0; ni < 4; ++ni) {
      u64 w = (u64)cvtpk(pb0[ni][0], pb0[ni][1]) | ((u64)cvtpk(pb0[ni][2], pb0[ni][3]) << 32);
      *(u64*)&PBT[0][(size_t)(ni * 16 + l15) * 68 + wq * 16 + lhi * 4] = w;
    }
  }
  __syncthreads();   // all waves done with Rs[1] before iter0 overwrites it

  f32x4 Oacc[4];
#pragma unroll
  for (int i = 0; i < 4; ++i) { f32x4 zz = {0.f, 0.f, 0.f, 0.f}; Oacc[i] = zz; }
  float mrow[4] = {-3.0e38f, -3.0e38f, -3.0e38f, -3.0e38f};
  float lrow[4] = {0.f, 0.f, 0.f, 0.f};

  for (int st = 0; st < nT; ++st) {
    const int b = st & 1;
    const bool lastT = (st == nT - 1);

    if (!lastT) {
      const int j1 = (st + 1) * 64;
      stageT(Kg + (size_t)j1 * 64, Ks[b ^ 1]);
      stageVf(j1, Vs[b ^ 1]);
      if (st + 1 < nT - 1)
        stageT(Rg + (size_t)(j1 - i0 + 512) * 64, Rs[b ^ 1]);
    }

    f32x4 cacc[4], pbh[4];
#pragma unroll
    for (int i = 0; i < 4; ++i) {
      f32x4 zz = {0.f, 0.f, 0.f, 0.f};
      cacc[i] = zz; pbh[i] = zz;
    }
    __builtin_amdgcn_s_setprio(1);
#pragma unroll
    for (int ks = 0; ks < 2; ++ks) {
#pragma unroll
      for (int ni = 0; ni < 4; ++ni) {
        const int brow = ni * 16 + l15;
        const bf16x8 bk_ = *(const bf16x8*)&Ks[b][brow * 64 + (((ks * 4 + lhi) ^ (brow & 7)) << 3)];
        cacc[ni] = __builtin_amdgcn_mfma_f32_16x16x32_bf16(au[ks], bk_, cacc[ni], 0, 0, 0);
      }
      if (!lastT) {
#pragma unroll
        for (int ni = 0; ni < 4; ++ni) {
          const int brow = ni * 16 + l15;
          const bf16x8 br_ = *(const bf16x8*)&Rs[b][brow * 64 + (((ks * 4 + lhi) ^ (brow & 7)) << 3)];
          pbh[ni] = __builtin_amdgcn_mfma_f32_16x16x32_bf16(av[ks], br_, pbh[ni], 0, 0, 0);
        }
      }
    }
    __builtin_amdgcn_s_setprio(0);

    if (!lastT) {
#pragma unroll
      for (int ni = 0; ni < 4; ++ni) {
        u64 w = (u64)cvtpk(pbh[ni][0], pbh[ni][1]) | ((u64)cvtpk(pbh[ni][2], pbh[ni][3]) << 32);
        *(u64*)&PBT[(st + 1) & 1][(size_t)(ni * 16 + l15) * 68 + wq * 16 + lhi * 4] = w;
      }
    }

    // ---- scores: add-only (pre-scaled); mask only on last tile ----
    const u16* pbLo = &PBT[st & 1][0];
    const u16* pbHi = &PBT[(st + 1) & 1][0];
    float sc[4][4];
#pragma unroll
    for (int ni = 0; ni < 4; ++ni) {
      const int dj = ni * 16 + l15;
#pragma unroll
      for (int qq = 0; qq < 4; ++qq) {
        const int di = wq * 16 + lhi * 4 + qq;
        const int cc = dj - di + 63;
        const float pb = b2f((cc < 64) ? pbLo[(size_t)cc * 68 + di]
                                       : pbHi[(size_t)(cc - 64) * 68 + di]);
        float s = cacc[ni][qq] + pb;
        if (lastT && dj > di) s = -1e30f;
        sc[ni][qq] = s;
      }
    }

    // ---- online softmax with T13 defer-max ----
    float r4[4];
    float dmax = -3.0e38f;
#pragma unroll
    for (int qq = 0; qq < 4; ++qq) {
      float r = fmaxf(fmaxf(sc[0][qq], sc[1][qq]), fmaxf(sc[2][qq], sc[3][qq]));
      r = fmaxf(r, __shfl_xor(r, 1));
      r = fmaxf(r, __shfl_xor(r, 2));
      r = fmaxf(r, __shfl_xor(r, 4));
      r = fmaxf(r, __shfl_xor(r, 8));
      r4[qq] = r;
      dmax = fmaxf(dmax, r - mrow[qq]);
    }
    const bool skip = __all(dmax <= 8.f);   // wave-uniform
    if (!skip) {
#pragma unroll
      for (int qq = 0; qq < 4; ++qq) {
        const float nm = fmaxf(mrow[qq], r4[qq]);
        const float esc = exp2f(mrow[qq] - nm);
        mrow[qq] = nm;
        lrow[qq] *= esc;
#pragma unroll
        for (int nd = 0; nd < 4; ++nd) Oacc[nd][qq] *= esc;
      }
    }
    float ps[4][4];
    float rsum[4] = {0.f, 0.f, 0.f, 0.f};
#pragma unroll
    for (int ni = 0; ni < 4; ++ni)
#pragma unroll
      for (int qq = 0; qq < 4; ++qq) {
        float p = exp2f(sc[ni][qq] - mrow[qq]);
        ps[ni][qq] = p;
        rsum[qq] += p;
      }
#pragma unroll
    for (int qq = 0; qq < 4; ++qq) {
      float r = rsum[qq];
      r += __shfl_xor(r, 1);
      r += __shfl_xor(r, 2);
      r += __shfl_xor(r, 4);
      r += __shfl_xor(r, 8);
      lrow[qq] += r;
    }

    // ---- P -> LDS (cvt_pk) -> PV MFMA ----
#pragma unroll
    for (int ni = 0; ni < 4; ++ni) {
      unsigned p01 = cvtpk(ps[ni][0], ps[ni][1]);
      unsigned p23 = cvtpk(ps[ni][2], ps[ni][3]);
      Ps[wq][lhi * 4 + 0][ni * 16 + l15] = (u16)p01;
      Ps[wq][lhi * 4 + 1][ni * 16 + l15] = (u16)(p01 >> 16);
      Ps[wq][lhi * 4 + 2][ni * 16 + l15] = (u16)p23;
      Ps[wq][lhi * 4 + 3][ni * 16 + l15] = (u16)(p23 >> 16);
    }
    __builtin_amdgcn_s_setprio(1);
#pragma unroll
    for (int ks = 0; ks < 2; ++ks) {
      const bf16x8 pa = *(const bf16x8*)&Ps[wq][l15][ks * 32 + lhi * 8];
#pragma unroll
      for (int nd = 0; nd < 4; ++nd) {
        const int vrow = nd * 16 + l15;
        const bf16x8 vb_ = *(const bf16x8*)&Vs[b][vrow * 64 + (((ks * 4 + lhi) ^ (vrow & 7)) << 3)];
        Oacc[nd] = __builtin_amdgcn_mfma_f32_16x16x32_bf16(pa, vb_, Oacc[nd], 0, 0, 0);
      }
    }
    __builtin_amdgcn_s_setprio(0);

    __syncthreads();
  }

  // epilogue
  float inv[4];
#pragma unroll
  for (int qq = 0; qq < 4; ++qq) inv[qq] = 1.f / lrow[qq];
  const int b = bh >> 4;
  const int rbase = i0 + wq * 16 + lhi * 4;
#pragma unroll
  for (int nd = 0; nd < 4; ++nd) {
    const int d = nd * 16 + l15;
    unsigned w01 = cvtpk(Oacc[nd][0] * inv[0], Oacc[nd][1] * inv[1]);
    unsigned w23 = cvtpk(Oacc[nd][2] * inv[2], Oacc[nd][3] * inv[3]);
    u16* yb = Y + (size_t)rbase * 8192 + b * 1024 + h * 64 + d;
    yb[0] = (u16)w01; yb[8192] = (u16)(w01 >> 16);
    yb[16384] = (u16)w23; yb[24576] = (u16)(w23 >> 16);
  }
}

// ---------------------------------------------------------------------------
__global__ __launch_bounds__(256) void biasprep(const float* __restrict__ bq,
                                                const float* __restrict__ u,
                                                const float* __restrict__ vb,
                                                float* __restrict__ bqu,
                                                float* __restrict__ dvb)
{
  const int i = blockIdx.x * 256 + threadIdx.x;
  bqu[i] = bq[i] + u[i];
  dvb[i] = vb[i] - u[i];
}

// ---------------------------------------------------------------------------
#define MAXW 20
struct WPack {
  const float* src[MAXW];
  u16* dst[MAXW];
  int K[MAXW], N[MAXW];
  int tilePrefix[MAXW + 1];
  int nm;
};

__global__ __launch_bounds__(256) void wtrans_kernel(WPack p) {
  int bid = blockIdx.x;
  int m = 0;
  while (m < p.nm && bid >= p.tilePrefix[m + 1]) ++m;
  if (m >= p.nm) return;
  const int lt = bid - p.tilePrefix[m];
  const int K = p.K[m], N = p.N[m];
  const int tN = N >> 5;
  const int kt = lt / tN, nt = lt - kt * tN;
  const int k0 = kt << 5, n0 = nt << 5;
  const float* src = p.src[m];
  u16* dst = p.dst[m];
  __shared__ float tile[32][33];
  const int t = threadIdx.x;
  const int r = t >> 3, c4 = (t & 7) << 2;
  float4 v = *(const float4*)&src[(size_t)(k0 + r) * N + n0 + c4];
  tile[r][c4 + 0] = v.x; tile[r][c4 + 1] = v.y; tile[r][c4 + 2] = v.z; tile[r][c4 + 3] = v.w;
  __syncthreads();
  u16 o0 = f2b(tile[c4 + 0][r]);
  u16 o1 = f2b(tile[c4 + 1][r]);
  u16 o2 = f2b(tile[c4 + 2][r]);
  u16 o3 = f2b(tile[c4 + 3][r]);
  u64 w = (u64)o0 | ((u64)o1 << 16) | ((u64)o2 << 32) | ((u64)o3 << 48);
  *(u64*)&dst[(size_t)(n0 + r) * K + k0 + c4] = w;
}

// ---------------------------------------------------------------------------
__global__ __launch_bounds__(256) void ln_kernel(
    const float* __restrict__ Xmem, const float* __restrict__ Xout, int rowsMem,
    const float* __restrict__ sc, const float* __restrict__ bi, u16* __restrict__ dst)
{
  const int row = blockIdx.x;
  const float* src = (row < rowsMem) ? (Xmem + (long long)row * 1024)
                                     : (Xout + (long long)(row - rowsMem) * 1024);
  const int t = threadIdx.x;
  float4 v = *(const float4*)&src[t * 4];
  float s1 = v.x + v.y + v.z + v.w;
  float s2 = v.x * v.x + v.y * v.y + v.z * v.z + v.w * v.w;
#pragma unroll
  for (int o = 32; o > 0; o >>= 1) { s1 += __shfl_down(s1, o); s2 += __shfl_down(s2, o); }
  __shared__ float red[8];
  const int wv = t >> 6;
  if ((t & 63) == 0) { red[wv * 2] = s1; red[wv * 2 + 1] = s2; }
  __syncthreads();
  s1 = red[0] + red[2] + red[4] + red[6];
  s2 = red[1] + red[3] + red[5] + red[7];
  const float mu = s1 * (1.f / 1024.f);
  const float var = s2 * (1.f / 1024.f) - mu * mu;
  const float rs = rsqrtf(var + 1e-5f);
  float vals[4] = {v.x, v.y, v.z, v.w};
  u16 o4[4];
#pragma unroll
  for (int j = 0; j < 4; ++j) {
    const int c = t * 4 + j;
    o4[j] = f2b((vals[j] - mu) * rs * sc[c] + bi[c]);
  }
  *(u64*)&dst[(long long)row * 1024 + t * 4] =
      (u64)o4[0] | ((u64)o4[1] << 16) | ((u64)o4[2] << 32) | ((u64)o4[3] << 48);
}

// ---------------------------------------------------------------------------
__global__ __launch_bounds__(256) void prep_vt16(const u16* __restrict__ Vf, u16* __restrict__ VT)
{
  const int f0 = blockIdx.x * 64;
  const int bh = blockIdx.y;
  const int b = bh >> 4, h = bh & 15;
  __shared__ u16 tl[64 * 65];
  const int t = threadIdx.x;
  {
    const int fr = t >> 2, c0 = (t & 3) * 16;
    const u16* src = Vf + ((size_t)(f0 + fr) * 8 + b) * 1024 + h * 64 + c0;
    bf16x8 v0 = *(const bf16x8*)src;
    bf16x8 v1 = *(const bf16x8*)(src + 8);
#pragma unroll
    for (int j = 0; j < 8; ++j) tl[fr * 65 + c0 + j] = (u16)v0[j];
#pragma unroll
    for (int j = 0; j < 8; ++j) tl[fr * 65 + c0 + 8 + j] = (u16)v1[j];
  }
  __syncthreads();
  {
    const int dr = t >> 2, c0 = (t & 3) * 16;
    u16* dst = VT + ((long long)bh * 64 + dr) * 1024 + f0 + c0;
#pragma unroll
    for (int j = 0; j < 16; ++j) dst[j] = tl[(c0 + j) * 65 + dr];
  }
}

__global__ __launch_bounds__(256) void pe_kernel(u16* __restrict__ PEB)
{
  const long long idx = (long long)blockIdx.x * 256 + threadIdx.x;
  const int p = (int)(idx >> 10);
  const int d = idx & 1023;
  const int q = d & 511;
  const float inv = powf(10000.f, -(float)(2 * q) * (1.f / 1024.f));
  const float ang = (float)(1023 - p) * inv;
  PEB[idx] = f2b((d < 512) ? sinf(ang) : cosf(ang));
}

__global__ __launch_bounds__(256) void embed_conv(const float* __restrict__ h, u16* __restrict__ A)
{
  const long long idx = (long long)blockIdx.x * 256 + threadIdx.x;
  const int c = idx & 127;
  const int r = (int)(idx >> 7);
  const int s = r >> 3, b = r & 7;
  A[idx] = f2b(h[(((long long)b * 512 + s) << 7) + c]);
}

// ---------------------------------------------------------------------------
// GRU elementwise, bf16 temps, 8 el/thread.
// ---------------------------------------------------------------------------
__global__ __launch_bounds__(256) void gru_elemA(const u16* __restrict__ T1, u16* __restrict__ T2,
                                                 const float* __restrict__ X, u16* __restrict__ RXBF)
{
  const long long i8 = ((long long)blockIdx.x * 256 + threadIdx.x) * 8;
  const int row = (int)(i8 >> 10);
  const int c = i8 & 1023;
  const u16* t1 = T1 + (long long)row * 3072 + c;
  u16* t2 = T2 + (long long)row * 2048 + c;
  bf16x8 ry = *(const bf16x8*)t1;
  bf16x8 zy = *(const bf16x8*)(t1 + 1024);
  bf16x8 rx = *(const bf16x8*)t2;
  bf16x8 zx = *(const bf16x8*)(t2 + 1024);
  float4 x0 = *(const float4*)(X + i8);
  float4 x1 = *(const float4*)(X + i8 + 4);
  float xs[8] = {x0.x, x0.y, x0.z, x0.w, x1.x, x1.y, x1.z, x1.w};
  u16 ro[8], zo[8];
#pragma unroll
  for (int j = 0; j < 8; ++j) {
    float r = sigm_f(b2f((u16)ry[j]) + b2f((u16)rx[j]));
    float z = sigm_f(b2f((u16)zy[j]) + b2f((u16)zx[j]) - 2.f);
    ro[j] = f2b(r * xs[j]);
    zo[j] = f2b(z);
  }
  *(u64*)&RXBF[i8] = (u64)ro[0] | ((u64)ro[1] << 16) | ((u64)ro[2] << 32) | ((u64)ro[3] << 48);
  *(u64*)&RXBF[i8 + 4] = (u64)ro[4] | ((u64)ro[5] << 16) | ((u64)ro[6] << 32) | ((u64)ro[7] << 48);
  *(u64*)&t2[0] = (u64)zo[0] | ((u64)zo[1] << 16) | ((u64)zo[2] << 32) | ((u64)zo[3] << 48);
  *(u64*)&t2[4] = (u64)zo[4] | ((u64)zo[5] << 16) | ((u64)zo[6] << 32) | ((u64)zo[7] << 48);
}

// tOut: 0 -> O[row][c] flat; 1 -> O[(b*512+s)][c] transposed (final output)
__global__ __launch_bounds__(256) void gru_elemB(const u16* __restrict__ T1, const u16* __restrict__ T2,
                                                 const u16* __restrict__ TG, const float* __restrict__ X,
                                                 float* __restrict__ O, u16* __restrict__ XBF, int tOut)
{
  const long long i8 = ((long long)blockIdx.x * 256 + threadIdx.x) * 8;
  const int row = (int)(i8 >> 10);
  const int c = i8 & 1023;
  bf16x8 gy = *(const bf16x8*)(T1 + (long long)row * 3072 + 2048 + c);
  bf16x8 tt = *(const bf16x8*)(TG + i8);
  bf16x8 zz = *(const bf16x8*)(T2 + (long long)row * 2048 + c);
  float4 x0 = *(const float4*)(X + i8);
  float4 x1 = *(const float4*)(X + i8 + 4);
  float xs[8] = {x0.x, x0.y, x0.z, x0.w, x1.x, x1.y, x1.z, x1.w};
  float os[8];
  u16 ob[8];
#pragma unroll
  for (int j = 0; j < 8; ++j) {
    float z = b2f((u16)zz[j]);
    float o = (1.f - z) * xs[j] + z * tanh_f(b2f((u16)gy[j]) + b2f((u16)tt[j]));
    os[j] = o;
    ob[j] = f2b(o);
  }
  float4 o0 = {os[0], os[1], os[2], os[3]};
  float4 o1 = {os[4], os[5], os[6], os[7]};
  long long oo = i8;
  if (tOut) {
    const int s = row >> 3, b = row & 7;
    oo = (((long long)b * 512 + s) << 10) + c;
  }
  *(float4*)(O + oo) = o0;
  *(float4*)(O + oo + 4) = o1;
  *(u64*)&XBF[i8] = (u64)ob[0] | ((u64)ob[1] << 16) | ((u64)ob[2] << 32) | ((u64)ob[3] << 48);
  *(u64*)&XBF[i8 + 4] = (u64)ob[4] | ((u64)ob[5] << 16) | ((u64)ob[6] << 32) | ((u64)ob[7] << 48);
}

// ---------------------------------------------------------------------------
extern "C" void kernel_launch(void* const* d_in, const int* in_sizes, int n_in,
                              void* d_out, int out_size, void* d_ws, size_t ws_size,
                              hipStream_t stream)
{
  (void)in_sizes; (void)n_in; (void)out_size; (void)ws_size;
  const float* h_in   = (const float*)d_in[0];
  const float* memory = (const float*)d_in[1];
  const float* We     = (const float*)d_in[2];
  const float* be     = (const float*)d_in[3];
  const float* ln1s   = (const float*)d_in[4];
  const float* ln1b   = (const float*)d_in[5];
  const float* ln2s   = (const float*)d_in[6];
  const float* ln2b   = (const float*)d_in[7];
  const float* Wq     = (const float*)d_in[8];
  const float* bq     = (const float*)d_in[9];
  const float* Wk     = (const float*)d_in[10];
  const float* bk     = (const float*)d_in[11];
  const float* Wv     = (const float*)d_in[12];
  const float* bv     = (const float*)d_in[13];
  const float* Wr     = (const float*)d_in[14];
  const float* br     = (const float*)d_in[15];
  const float* Wo     = (const float*)d_in[16];
  const float* bo     = (const float*)d_in[17];
  const float* uu     = (const float*)d_in[18];
  const float* vbp    = (const float*)d_in[19];
  const float* gWr    = (const float*)d_in[20];
  const float* gUr    = (const float*)d_in[21];
  const float* gWz    = (const float*)d_in[22];
  const float* gUz    = (const float*)d_in[23];
  const float* gWg    = (const float*)d_in[24];
  const float* gUg    = (const float*)d_in[25];
  const float* fW1    = (const float*)d_in[26];
  const float* fb1    = (const float*)d_in[27];
  const float* fW2    = (const float*)d_in[28];
  const float* fb2    = (const float*)d_in[29];

  constexpr int S = 512, MM = 512, B = 8, D = 1024, H = 16, IN = 128, F = 1024;
  constexpr int SB = 4096, FB = 8192;
  constexpr long long DD = (long long)D * D;

  char* ws = (char*)d_ws;
  size_t off = 0;
  auto alloc = [&](size_t bytes) -> size_t {
    size_t o = off; off = (off + bytes + 255) & ~(size_t)255; return o;
  };
  const size_t oWT   = alloc((size_t)25 * DD * 2);
  const size_t oWET  = alloc((size_t)D * IN * 2);
  const size_t oPEB  = alloc((size_t)F * D * 2);
  const size_t oOUT  = alloc((size_t)SB * D * 4);
  const size_t oOUT1 = alloc((size_t)SB * D * 4);
  const size_t oXBF  = alloc((size_t)SB * D * 2);
  const size_t oYBF  = alloc((size_t)SB * D * 2);
  const size_t oYBFA = alloc((size_t)SB * D * 2);
  const size_t oABUF = alloc((size_t)SB * D * 2);
  const size_t oKN   = alloc((size_t)FB * D * 2);
  const size_t oQU   = alloc((size_t)B * H * S * 64 * 2);
  const size_t oQV   = alloc((size_t)B * H * S * 64 * 2);
  const size_t oKBH  = alloc((size_t)B * H * F * 64 * 2);
  const size_t oVT   = alloc((size_t)B * H * F * 64 * 2);
  const size_t oRH   = alloc((size_t)H * F * 64 * 2);
  const size_t oBQU  = alloc((size_t)D * 4);
  const size_t oDVB  = alloc((size_t)D * 4);
  const size_t oUNI  = off;

  u16* WTp   = (u16*)(ws + oWT);
  u16* WETp  = (u16*)(ws + oWET);
  u16* PEBp  = (u16*)(ws + oPEB);
  float* OUTp  = (float*)(ws + oOUT);
  float* OUT1p = (float*)(ws + oOUT1);
  u16* XBFp  = (u16*)(ws + oXBF);
  u16* YBFp  = (u16*)(ws + oYBF);
  u16* YBFAp = (u16*)(ws + oYBFA);
  u16* ABUFp = (u16*)(ws + oABUF);
  u16* KNp   = (u16*)(ws + oKN);
  u16* QUp   = (u16*)(ws + oQU);
  u16* QVp   = (u16*)(ws + oQV);
  u16* KBHp  = (u16*)(ws + oKBH);
  u16* VTp   = (u16*)(ws + oVT);
  u16* RHp   = (u16*)(ws + oRH);
  float* bquP = (float*)(ws + oBQU);
  float* dvbP = (float*)(ws + oDVB);
  u16* VF16p  = (u16*)(ws + oUNI);
  u16* T1p    = (u16*)(ws + oUNI);                                   // SB x 3072 bf16
  u16* T2p    = (u16*)(ws + oUNI + (size_t)SB * 3 * D * 2 + 256);    // SB x 2048 bf16
  u16* TGp    = (u16*)(ws + oUNI + (size_t)SB * 5 * D * 2 + 512);    // SB x 1024 bf16
  u16* FFNBp  = (u16*)(ws + oUNI);

  auto gemm = [&](const u16* A, const u16* Bt, const float* bias, const float* bias2,
                  float* C32, u16* C16, u16* C16b,
                  int M, int N, int K, int ldA, int ldB, int ldC,
                  long long sA, long long sBb, long long sBh, long long sC, int nH, int Z,
                  int flags) {
    if (M >= 2048 && N >= 2048 && (N % 128) == 0) {
      dim3 grid((M + 127) / 128, N / 128, Z);
      gemm_bt<512, 128><<<grid, 512, 0, stream>>>(A, Bt, bias, bias2, C32, C16, C16b,
                                                  M, N, K, ldA, ldB, ldC,
                                                  sA, sBb, sBh, sC, nH, flags);
    } else {
      dim3 grid((M + 127) / 128, (N + 63) / 64, Z);
      gemm_bt<256, 64><<<grid, 256, 0, stream>>>(A, Bt, bias, bias2, C32, C16, C16b,
                                                 M, N, K, ldA, ldB, ldC,
                                                 sA, sBb, sBh, sC, nH, flags);
    }
  };

  pe_kernel<<<(F * D) / 256, 256, 0, stream>>>(PEBp);
  {
    WPack p{};
    p.nm = 1; p.src[0] = We; p.dst[0] = WETp; p.K[0] = IN; p.N[0] = D;
    p.tilePrefix[0] = 0; p.tilePrefix[1] = (IN / 32) * (D / 32);
    wtrans_kernel<<<p.tilePrefix[1], 256, 0, stream>>>(p);
  }
  embed_conv<<<(SB * IN) / 256, 256, 0, stream>>>(h_in, ABUFp);
  gemm(ABUFp, WETp, be, nullptr, OUTp, XBFp, nullptr, SB, D, IN, IN, IN, D,
       0, 0, 0, 0, 1, 1, 1 | 2 | 4 | 8);

  for (int li = 0; li < 4; ++li) {
    WPack p{};
    int nt = 0, id = 0;
    auto addw = [&](const float* s, u16* d, int K, int N) {
      p.src[id] = s; p.dst[id] = d; p.K[id] = K; p.N[id] = N;
      p.tilePrefix[id] = nt; nt += (K / 32) * (N / 32); ++id;
    };
    addw(Wq + li * DD, WTp + 0 * DD, D, D);
    addw(Wk + li * DD, WTp + 1 * DD, D, D);
    addw(Wv + li * DD, WTp + 2 * DD, D, D);
    addw(Wr + li * DD, WTp + 3 * DD, D, D);
    addw(Wo + li * DD, WTp + 4 * DD, D, D);
    addw(gWr + (li * 2 + 0) * DD, WTp + 5 * DD, D, D);
    addw(gWz + (li * 2 + 0) * DD, WTp + 6 * DD, D, D);
    addw(gWg + (li * 2 + 0) * DD, WTp + 7 * DD, D, D);
    addw(gUr + (li * 2 + 0) * DD, WTp + 8 * DD, D, D);
    addw(gUz + (li * 2 + 0) * DD, WTp + 9 * DD, D, D);
    addw(gUg + (li * 2 + 0) * DD, WTp + 10 * DD, D, D);
    addw(gWr + (li * 2 + 1) * DD, WTp + 11 * DD, D, D);
    addw(gWz + (li * 2 + 1) * DD, WTp + 12 * DD, D, D);
    addw(gWg + (li * 2 + 1) * DD, WTp + 13 * DD, D, D);
    addw(gUr + (li * 2 + 1) * DD, WTp + 14 * DD, D, D);
    addw(gUz + (li * 2 + 1) * DD, WTp + 15 * DD, D, D);
    addw(gUg + (li * 2 + 1) * DD, WTp + 16 * DD, D, D);
    addw(fW1 + li * (long long)D * 4096, WTp + 17 * DD, D, 4096);
    addw(fW2 + li * (long long)4096 * D, WTp + 21 * DD, 4096, D);
    p.tilePrefix[id] = nt; p.nm = id;
    wtrans_kernel<<<nt, 256, 0, stream>>>(p);

    ln_kernel<<<FB, 256, 0, stream>>>(memory + (long long)li * MM * B * D, OUTp, MM * B,
                                      ln1s + li * D, ln1b + li * D, KNp);
    const u16* QN = KNp + (size_t)MM * B * D;

    // ---- projections: dual-Q (KSC-scaled) + merged K/V ----
    biasprep<<<4, 256, 0, stream>>>(bq + li * D, uu + li * D, vbp + li * D, bquP, dvbP);
    gemm(QN, WTp + 0 * DD, bquP, dvbP, nullptr, QUp, QVp, SB, D, D, D, D, /*seq*/ S,
         0, 0, 0, 0, 1, 1, 2 | 64);
    gemm(KNp, WTp + 1 * DD, bk + li * D, bv + li * D, nullptr, KBHp, VF16p,
         FB, D, D, D, D, /*seq*/ F, 0, 0, DD, 0, 2, 2, 2 | 128);
    prep_vt16<<<dim3(F / 64, B * H), 256, 0, stream>>>(VF16p, VTp);
    gemm(PEBp, WTp + 3 * DD, br + li * D, nullptr, nullptr, RHp, nullptr,
         F, D, D, D, D, D, 0, 0, 0, 0, 1, 1, 2 | 8 | 32);

    // ---- fused attention ----
    fused_attn<<<dim3((S / 64) * B * H), 256, 0, stream>>>(QUp, QVp, KBHp, VTp, RHp, YBFAp);

    // ---- output projection ----
    gemm(YBFAp, WTp + 4 * DD, bo + li * D, nullptr, nullptr, YBFp, nullptr,
         SB, D, D, D, D, D, 0, 0, 0, 0, 1, 1, 1 | 2 | 8);

    // ---- GRU1 (bf16 temps) ----
    gemm(YBFp, WTp + 5 * DD, nullptr, nullptr, nullptr, T1p, nullptr,
         SB, 3 * D, D, D, D, 3 * D, 0, 0, 0, 0, 1, 1, 8);
    gemm(XBFp, WTp + 8 * DD, nullptr, nullptr, nullptr, T2p, nullptr,
         SB, 2 * D, D, D, D, 2 * D, 0, 0, 0, 0, 1, 1, 8);
    gru_elemA<<<(SB * D / 8) / 256, 256, 0, stream>>>(T1p, T2p, OUTp, ABUFp);
    gemm(ABUFp, WTp + 10 * DD, nullptr, nullptr, nullptr, TGp, nullptr,
         SB, D, D, D, D, D, 0, 0, 0, 0, 1, 1, 8);
    gru_elemB<<<(SB * D / 8) / 256, 256, 0, stream>>>(T1p, T2p, TGp, OUTp, OUT1p, XBFp, 0);

    // ---- FFN ----
    ln_kernel<<<SB, 256, 0, stream>>>(OUT1p, OUT1p, SB, ln2s + li * D, ln2b + li * D, ABUFp);
    gemm(ABUFp, WTp + 17 * DD, fb1 + li * 4096, nullptr, nullptr, FFNBp, nullptr,
         SB, 4096, D, D, D, 4096, 0, 0, 0, 0, 1, 1, 1 | 2 | 8);
    gemm(FFNBp, WTp + 21 * DD, fb2 + li * D, nullptr, nullptr, YBFp, nullptr,
         SB, D, 4096, 4096, 4096, D, 0, 0, 0, 0, 1, 1, 1 | 2 | 8);

    // ---- GRU2 (bf16 temps; last layer writes transposed O to d_out) ----
    gemm(YBFp, WTp + 11 * DD, nullptr, nullptr, nullptr, T1p, nullptr,
         SB, 3 * D, D, D, D, 3 * D, 0, 0, 0, 0, 1, 1, 8);
    gemm(XBFp, WTp + 14 * DD, nullptr, nullptr, nullptr, T2p, nullptr,
         SB, 2 * D, D, D, D, 2 * D, 0, 0, 0, 0, 1, 1, 8);
    gru_elemA<<<(SB * D / 8) / 256, 256, 0, stream>>>(T1p, T2p, OUT1p, ABUFp);
    gemm(ABUFp, WTp + 16 * DD, nullptr, nullptr, nullptr, TGp, nullptr,
         SB, D, D, D, D, D, 0, 0, 0, 0, 1, 1, 8);
    gru_elemB<<<(SB * D / 8) / 256, 256, 0, stream>>>(
        T1p, T2p, TGp, OUT1p, (li == 3) ? (float*)d_out : OUTp, XBFp, (li == 3) ? 1 : 0);
  }
}